// Round 1
// baseline (235.445 us; speedup 1.0000x reference)
//
#include <hip/hip_runtime.h>
#include <math.h>

// ---- problem constants ----
#define BATCH 512
#define CHAN 3
#define IMG 112
#define HW (IMG*IMG)            // 12544
#define K_TOT (CHAN*HW)         // 37632
#define NH 20
#define F4_TOT (K_TOT/4)        // 9408
#define KT 4                    // k-tiles
#define F4_PER_TILE (F4_TOT/KT) // 2352
#define MB 4                    // batches per block (register-blocked)

// Kernel 1: partial h = img @ W1 over a K-chunk, for 4 batches per block.
// grid (KT, 512/MB), block 256. Writes partial[kt][b][n] (deterministic, no atomics).
__global__ __launch_bounds__(256, 2)
void gemm1_kernel(const float* __restrict__ img, const float* __restrict__ W1,
                  float* __restrict__ partial) {
    const int tid = threadIdx.x;
    const int kt  = blockIdx.x;
    const int b0  = blockIdx.y * MB;
    const long base = (long)b0 * K_TOT;

    float acc[MB][NH];
    #pragma unroll
    for (int i = 0; i < MB; ++i)
        #pragma unroll
        for (int n = 0; n < NH; ++n) acc[i][n] = 0.f;

    const int f4start = kt * F4_PER_TILE;
    const int f4end   = f4start + F4_PER_TILE;

    for (int f = f4start + tid; f < f4end; f += 256) {
        const int k = f * 4;
        float4 iv[MB];
        #pragma unroll
        for (int i = 0; i < MB; ++i)
            iv[i] = *reinterpret_cast<const float4*>(img + base + (long)i * K_TOT + k);

        #pragma unroll
        for (int j = 0; j < 4; ++j) {
            const float4* wr = reinterpret_cast<const float4*>(W1 + (long)(k + j) * NH);
            float4 wq[5];
            #pragma unroll
            for (int q = 0; q < 5; ++q) wq[q] = wr[q];
            const float* wf = reinterpret_cast<const float*>(wq);
            #pragma unroll
            for (int i = 0; i < MB; ++i) {
                const float xi = reinterpret_cast<const float*>(&iv[i])[j];
                #pragma unroll
                for (int n = 0; n < NH; ++n)
                    acc[i][n] = fmaf(xi, wf[n], acc[i][n]);
            }
        }
    }

    // wave butterfly reduction (all 64 lanes end with full wave sum)
    __shared__ float red[4][MB * NH];
    const int wave = tid >> 6, lane = tid & 63;
    #pragma unroll
    for (int i = 0; i < MB; ++i)
        #pragma unroll
        for (int n = 0; n < NH; ++n) {
            float v = acc[i][n];
            #pragma unroll
            for (int off = 32; off > 0; off >>= 1) v += __shfl_xor(v, off, 64);
            if (lane == 0) red[wave][i * NH + n] = v;
        }
    __syncthreads();
    if (tid < MB * NH) {
        float s = red[0][tid] + red[1][tid] + red[2][tid] + red[3][tid];
        const int i = tid / NH, n = tid - i * NH;
        partial[((long)kt * BATCH + (b0 + i)) * NH + n] = s;
    }
}

// Kernel 2: theta[b][j] = tanh( b2[j] + sum_n tanh(h_raw[b][n] + b1[n]) * W2[n][j] )
__global__ __launch_bounds__(256)
void theta_kernel(const float* __restrict__ partial, const float* __restrict__ b1,
                  const float* __restrict__ W2, const float* __restrict__ b2,
                  float* __restrict__ theta) {
    const int b = blockIdx.x * 256 + threadIdx.x;
    if (b >= BATCH) return;
    float h[NH];
    #pragma unroll
    for (int n = 0; n < NH; ++n) {
        float s = b1[n];
        #pragma unroll
        for (int kt = 0; kt < KT; ++kt)
            s += partial[((long)kt * BATCH + b) * NH + n];
        h[n] = tanhf(s);
    }
    #pragma unroll
    for (int j = 0; j < 6; ++j) {
        float s = b2[j];
        #pragma unroll
        for (int n = 0; n < NH; ++n) s = fmaf(h[n], W2[n * 6 + j], s);
        theta[b * 6 + j] = tanhf(s);
    }
}

// Kernel 3: affine_grid + grid_sample (bilinear, zeros padding, align_corners=False)
// grid (HW/256, BATCH), block 256; one thread per pixel, all 3 channels.
__global__ __launch_bounds__(256)
void warp_kernel(const float* __restrict__ img, const float* __restrict__ theta,
                 float* __restrict__ out) {
    const int b   = blockIdx.y;
    const int pix = blockIdx.x * 256 + threadIdx.x;   // [0, 12544)
    const int y = pix / IMG;
    const int x = pix - y * IMG;

    const float* t = theta + b * 6;
    const float xs = (2.f * x + 1.f) / (float)IMG - 1.f;
    const float ys = (2.f * y + 1.f) / (float)IMG - 1.f;
    const float gx = t[0] * xs + t[1] * ys + t[2];
    const float gy = t[3] * xs + t[4] * ys + t[5];

    const float ix = ((gx + 1.f) * (float)IMG - 1.f) * 0.5f;
    const float iy = ((gy + 1.f) * (float)IMG - 1.f) * 0.5f;

    const float x0f = floorf(ix), y0f = floorf(iy);
    const float wx1 = ix - x0f, wx0 = 1.f - wx1;
    const float wy1 = iy - y0f, wy0 = 1.f - wy1;
    const int x0 = (int)x0f, y0 = (int)y0f;
    const int x1 = x0 + 1, y1 = y0 + 1;

    const bool vx0 = (x0 >= 0) & (x0 <= IMG - 1);
    const bool vx1 = (x1 >= 0) & (x1 <= IMG - 1);
    const bool vy0 = (y0 >= 0) & (y0 <= IMG - 1);
    const bool vy1 = (y1 >= 0) & (y1 <= IMG - 1);
    const int cx0 = min(max(x0, 0), IMG - 1), cx1 = min(max(x1, 0), IMG - 1);
    const int cy0 = min(max(y0, 0), IMG - 1), cy1 = min(max(y1, 0), IMG - 1);

    const float w00 = (vx0 && vy0) ? wx0 * wy0 : 0.f;
    const float w10 = (vx1 && vy0) ? wx1 * wy0 : 0.f;
    const float w01 = (vx0 && vy1) ? wx0 * wy1 : 0.f;
    const float w11 = (vx1 && vy1) ? wx1 * wy1 : 0.f;

    const long ib = (long)b * CHAN * HW;
    const int o00 = cy0 * IMG + cx0, o10 = cy0 * IMG + cx1;
    const int o01 = cy1 * IMG + cx0, o11 = cy1 * IMG + cx1;
    #pragma unroll
    for (int c = 0; c < CHAN; ++c) {
        const float* p = img + ib + (long)c * HW;
        const float v = w00 * p[o00] + w10 * p[o10] + w01 * p[o01] + w11 * p[o11];
        out[ib + (long)c * HW + pix] = v;
    }
}

extern "C" void kernel_launch(void* const* d_in, const int* in_sizes, int n_in,
                              void* d_out, int out_size, void* d_ws, size_t ws_size,
                              hipStream_t stream) {
    const float* img = (const float*)d_in[0];
    const float* W1  = (const float*)d_in[1];
    const float* b1  = (const float*)d_in[2];
    const float* W2  = (const float*)d_in[3];
    const float* b2  = (const float*)d_in[4];
    float* out = (float*)d_out;

    float* partial = (float*)d_ws;                  // [KT][512][20]
    float* theta   = partial + (long)KT * BATCH * NH; // [512][6]

    gemm1_kernel<<<dim3(KT, BATCH / MB), 256, 0, stream>>>(img, W1, partial);
    theta_kernel<<<dim3((BATCH + 255) / 256), 256, 0, stream>>>(partial, b1, W2, b2, theta);
    warp_kernel<<<dim3(HW / 256, BATCH), 256, 0, stream>>>(img, theta, out);
}